// Round 4
// baseline (1201.376 us; speedup 1.0000x reference)
//
#include <hip/hip_runtime.h>

// MSDeformAttn pixel decoder. v3: LDS-transpose flatten, deform 16thr/query,
// qb fused into LN2 epilogue. bf16-MFMA GEMMs (fused qproj|val N=640).
// D=256, NH=8, DH=32, NL=3, NP=4, DFF=1024, B=4, Q=5376, M=B*Q=21504.

#define DMODEL 256
#define NLAYERS 6
#define BATCH 4
#define QTOT 5376
#define MROWS (BATCH * QTOT)   // 21504 = 168*128

typedef __bf16 bf16x8 __attribute__((ext_vector_type(8)));
typedef __bf16 bf16x4 __attribute__((ext_vector_type(4)));
typedef float floatx4 __attribute__((ext_vector_type(4)));

// ---------------------------------------------------------------------------
// Flatten via LDS tile transpose. Per block: one 32x32 (d x p) tile of one
// (batch, level). Writes x fp32, xb bf16, pos fp32, qb bf16.
// Tiles per batch: L0 128*8=1024, L1 32*8=256, L2 8*8=64 -> 1344.
// ---------------------------------------------------------------------------
__global__ __launch_bounds__(256) void flatten_kernel(
    const float* __restrict__ s0, const float* __restrict__ p0,
    const float* __restrict__ s1, const float* __restrict__ p1,
    const float* __restrict__ s2, const float* __restrict__ p2,
    const float* __restrict__ lvl, float* __restrict__ x,
    float* __restrict__ pos, __bf16* __restrict__ xb,
    __bf16* __restrict__ qb) {
  __shared__ float ls[32][33];
  __shared__ float lp[32][33];
  int b = blockIdx.y;
  int tile = blockIdx.x;
  const float* sp; const float* pp; int l, hw, tp, td, qbase;
  if (tile < 1024)      { l = 0; hw = 4096; int t = tile;        td = t & 7; tp = t >> 3; qbase = 0; sp = s0; pp = p0; }
  else if (tile < 1280) { l = 1; hw = 1024; int t = tile - 1024; td = t & 7; tp = t >> 3; qbase = 4096; sp = s1; pp = p1; }
  else                  { l = 2; hw = 256;  int t = tile - 1280; td = t & 7; tp = t >> 3; qbase = 5120; sp = s2; pp = p2; }
  int tx = threadIdx.x & 31, ty = threadIdx.x >> 5;
  int d0 = td * 32, pbase = tp * 32;
#pragma unroll
  for (int r = 0; r < 4; ++r) {
    int dl = r * 8 + ty;
    size_t gi = ((size_t)(b * DMODEL + d0 + dl)) * hw + pbase + tx;
    ls[dl][tx] = sp[gi];
    lp[dl][tx] = pp[gi];
  }
  __syncthreads();
  int d = d0 + tx;
  float lv = lvl[l * DMODEL + d];
#pragma unroll
  for (int r = 0; r < 4; ++r) {
    int pl = r * 8 + ty;
    size_t bq = (size_t)b * QTOT + qbase + pbase + pl;
    float xv = ls[tx][pl];
    float pv = lp[tx][pl] + lv;
    x[bq * DMODEL + d] = xv;
    xb[bq * DMODEL + d] = (__bf16)xv;
    pos[bq * DMODEL + d] = pv;
    qb[bq * DMODEL + d] = (__bf16)(xv + pv);
  }
}

// ---------------------------------------------------------------------------
// Weight pack: W [L][K][N] fp32 -> Wt [L][N][K] bf16 (transposed)
// ---------------------------------------------------------------------------
__global__ __launch_bounds__(256) void pack_wt_kernel(
    const float* __restrict__ W, __bf16* __restrict__ Wt, int K, int N) {
  int l = blockIdx.y;
  int idx = blockIdx.x * 256 + threadIdx.x;
  int n = idx / K, k = idx - n * K;
  Wt[(size_t)l * N * K + idx] = (__bf16)W[(size_t)l * K * N + (size_t)k * N + n];
}

// Combined [W_off|W_attn|pad|W_val] pack -> Wt [L][640][256] bf16 + bias [L][640]
__global__ __launch_bounds__(256) void pack_qv_kernel(
    const float* __restrict__ Woff, const float* __restrict__ Wattn,
    const float* __restrict__ Wval,
    const float* __restrict__ boff, const float* __restrict__ battn,
    const float* __restrict__ bval,
    __bf16* __restrict__ Wt, float* __restrict__ bc) {
  int l = blockIdx.y;
  int n = blockIdx.x;          // 0..639
  int k = threadIdx.x;         // 0..255
  float v = 0.f;
  if (n < 192)      v = Woff[((size_t)l * 256 + k) * 192 + n];
  else if (n < 288) v = Wattn[((size_t)l * 256 + k) * 96 + (n - 192)];
  else if (n >= 384) v = Wval[((size_t)l * 256 + k) * 256 + (n - 384)];
  Wt[((size_t)l * 640 + n) * 256 + k] = (__bf16)v;
  if (k == 0) {
    float b = 0.f;
    if (n < 192)      b = boff[l * 192 + n];
    else if (n < 288) b = battn[l * 96 + (n - 192)];
    else if (n >= 384) b = bval[l * 256 + (n - 384)];
    bc[l * 640 + n] = b;
  }
}

// ---------------------------------------------------------------------------
// Shared MFMA tile core: acc[4][4] over 128x128 tile, BK=32, 4 waves (2x2).
// ---------------------------------------------------------------------------
#define GEMM_CORE(A_, B_, K_)                                                  \
  for (int k0 = 0; k0 < (K_); k0 += 32) {                                      \
    __syncthreads();                                                           \
    _Pragma("unroll")                                                          \
    for (int cc = 0; cc < 2; ++cc) {                                           \
      int c = wid * 2 + cc;                                                    \
      __builtin_amdgcn_global_load_lds(                                        \
          (__attribute__((address_space(1))) void*)((A_) + (size_t)c * 16 * (K_) + k0), \
          (__attribute__((address_space(3))) void*)(As + c * 512), 16, 0, 0);  \
      __builtin_amdgcn_global_load_lds(                                        \
          (__attribute__((address_space(1))) void*)((B_) + (size_t)c * 16 * (K_) + k0), \
          (__attribute__((address_space(3))) void*)(Bs + c * 512), 16, 0, 0);  \
    }                                                                          \
    __syncthreads();                                                           \
    bf16x8 af[4], bfr[4];                                                      \
    _Pragma("unroll")                                                          \
    for (int i = 0; i < 4; ++i)                                                \
      af[i] = *(const bf16x8*)&As[(wr * 64 + i * 16 + (lane & 15)) * 32 + (lane >> 4) * 8]; \
    _Pragma("unroll")                                                          \
    for (int j = 0; j < 4; ++j)                                                \
      bfr[j] = *(const bf16x8*)&Bs[(wc * 64 + j * 16 + (lane & 15)) * 32 + (lane >> 4) * 8]; \
    _Pragma("unroll")                                                          \
    for (int i = 0; i < 4; ++i)                                                \
      _Pragma("unroll")                                                        \
      for (int j = 0; j < 4; ++j)                                              \
        acc[i][j] = __builtin_amdgcn_mfma_f32_16x16x32_bf16(af[i], bfr[j], acc[i][j], 0, 0, 0); \
  }

// ---------------------------------------------------------------------------
// Generic bf16 GEMM: C = A[M,K] @ Wt[N,K]^T + bias
// ---------------------------------------------------------------------------
template<int RELU, int BF16OUT>
__global__ __launch_bounds__(256) void gemm_bf16_kernel(
    const __bf16* __restrict__ A, const __bf16* __restrict__ Wt,
    const float* __restrict__ bias, float* __restrict__ C,
    __bf16* __restrict__ Cb, int N, int K) {
  __shared__ __bf16 As[128 * 32];
  __shared__ __bf16 Bs[128 * 32];
  int t = threadIdx.x;
  int lane = t & 63, wid = t >> 6;
  int wr = wid >> 1, wc = wid & 1;
  int row0 = blockIdx.y * 128;
  int n0 = blockIdx.x * 128;
  floatx4 acc[4][4] = {};
  int srow = lane >> 2;
  int skoff = (lane & 3) * 8;
  const __bf16* Abase = A + (size_t)(row0 + srow) * K + skoff;
  const __bf16* Bbase = Wt + (size_t)(n0 + srow) * K + skoff;
  GEMM_CORE(Abase, Bbase, K)
  int orow = row0 + wr * 64 + (lane >> 4) * 4;
  int ocol = n0 + wc * 64 + (lane & 15);
#pragma unroll
  for (int i = 0; i < 4; ++i)
#pragma unroll
    for (int j = 0; j < 4; ++j) {
      int col = ocol + j * 16;
      float bv = bias[col];
#pragma unroll
      for (int r = 0; r < 4; ++r) {
        int row = orow + i * 16 + r;
        float v = acc[i][j][r] + bv;
        if (RELU) v = fmaxf(v, 0.f);
        if (BF16OUT) Cb[(size_t)row * N + col] = (__bf16)v;
        else         C[(size_t)row * N + col] = v;
      }
    }
}

// ---------------------------------------------------------------------------
// Fused [qproj|val] GEMM: bn<3 -> qproj (stride 384), bn>=3 -> val (stride 256)
// ---------------------------------------------------------------------------
__global__ __launch_bounds__(256) void gemm_qv_kernel(
    const __bf16* __restrict__ qb, const __bf16* __restrict__ xb,
    const __bf16* __restrict__ Wt, const float* __restrict__ bias,
    float* __restrict__ qproj, float* __restrict__ val) {
  __shared__ __bf16 As[128 * 32];
  __shared__ __bf16 Bs[128 * 32];
  int t = threadIdx.x;
  int lane = t & 63, wid = t >> 6;
  int wr = wid >> 1, wc = wid & 1;
  int bn = blockIdx.x;                    // 0..4
  int row0 = blockIdx.y * 128;
  int n0 = bn * 128;
  const __bf16* A = (bn < 3) ? qb : xb;
  floatx4 acc[4][4] = {};
  int srow = lane >> 2;
  int skoff = (lane & 3) * 8;
  const __bf16* Abase = A + (size_t)(row0 + srow) * 256 + skoff;
  const __bf16* Bbase = Wt + (size_t)(n0 + srow) * 256 + skoff;
  GEMM_CORE(Abase, Bbase, 256)
  float* C; int cstride, cbase;
  if (bn < 3) { C = qproj; cstride = 384; cbase = n0; }
  else        { C = val;   cstride = 256; cbase = n0 - 384; }
  int orow = row0 + wr * 64 + (lane >> 4) * 4;
  int ocol = wc * 64 + (lane & 15);
#pragma unroll
  for (int i = 0; i < 4; ++i)
#pragma unroll
    for (int j = 0; j < 4; ++j) {
      int col = ocol + j * 16;
      float bv = bias[n0 + col];
#pragma unroll
      for (int r = 0; r < 4; ++r) {
        int row = orow + i * 16 + r;
        C[(size_t)row * cstride + cbase + col] = acc[i][j][r] + bv;
      }
    }
}

// ---------------------------------------------------------------------------
// Deformable sampling + per-head softmax. 16 threads/query: hid = tq>>1,
// 16 channels (4x float4) per thread. Output bf16.
// ---------------------------------------------------------------------------
__global__ __launch_bounds__(256) void deform_kernel(
    const float* __restrict__ val, const float* __restrict__ qproj,
    __bf16* __restrict__ out) {
  int bq = blockIdx.x * 16 + (threadIdx.x >> 4);
  int b = bq / QTOT, q = bq % QTOT;
  int tq = threadIdx.x & 15;
  int hid = tq >> 1, dq = (tq & 1) * 16;

  int p, wsrc;
  if (q < 4096)      { p = q;        wsrc = 64; }
  else if (q < 5120) { p = q - 4096; wsrc = 32; }
  else               { p = q - 5120; wsrc = 16; }
  float inv = 1.0f / (float)wsrc;
  float refx = ((float)(p % wsrc) + 0.5f) * inv;
  float refy = ((float)(p / wsrc) + 0.5f) * inv;

  const float* base = qproj + (size_t)bq * 384;
  float aw[12], ob[24];
  *(float4*)&aw[0] = *(const float4*)(base + 192 + hid * 12);
  *(float4*)&aw[4] = *(const float4*)(base + 192 + hid * 12 + 4);
  *(float4*)&aw[8] = *(const float4*)(base + 192 + hid * 12 + 8);
#pragma unroll
  for (int i = 0; i < 6; ++i)
    *(float4*)&ob[i * 4] = *(const float4*)(base + hid * 24 + i * 4);

  float mx = -1e30f;
#pragma unroll
  for (int k = 0; k < 12; ++k) mx = fmaxf(mx, aw[k]);
  float s = 0.f;
#pragma unroll
  for (int k = 0; k < 12; ++k) { aw[k] = __expf(aw[k] - mx); s += aw[k]; }
  float invs = 1.0f / s;

  const float* vb = val + ((size_t)b * QTOT) * DMODEL + hid * 32 + dq;

  const int starts[3] = {0, 4096, 5120};
  const int wls[3] = {64, 32, 16};
  float4 a0 = {0,0,0,0}, a1 = {0,0,0,0}, a2 = {0,0,0,0}, a3 = {0,0,0,0};
#pragma unroll
  for (int l = 0; l < 3; ++l) {
    int wl = wls[l], start = starts[l];
    float fwl = (float)wl;
#pragma unroll
    for (int pp = 0; pp < 4; ++pp) {
      float wcomb = aw[l * 4 + pp] * invs;
      float fx = refx * fwl + ob[(l * 4 + pp) * 2 + 0] - 0.5f;
      float fy = refy * fwl + ob[(l * 4 + pp) * 2 + 1] - 0.5f;
      float x0f = floorf(fx), y0f = floorf(fy);
      float lx = fx - x0f, ly = fy - y0f;
      int x0 = (int)x0f, y0 = (int)y0f;
#pragma unroll
      for (int c = 0; c < 4; ++c) {
        int dx = c & 1, dy = c >> 1;
        int xi = x0 + dx, yi = y0 + dy;
        if (xi >= 0 && xi < wl && yi >= 0 && yi < wl) {
          float wgt = (dx ? lx : 1.f - lx) * (dy ? ly : 1.f - ly) * wcomb;
          const float* vp = vb + (size_t)(start + yi * wl + xi) * DMODEL;
          float4 v0 = *(const float4*)(vp + 0);
          float4 v1 = *(const float4*)(vp + 4);
          float4 v2 = *(const float4*)(vp + 8);
          float4 v3 = *(const float4*)(vp + 12);
          a0.x = fmaf(wgt, v0.x, a0.x); a0.y = fmaf(wgt, v0.y, a0.y);
          a0.z = fmaf(wgt, v0.z, a0.z); a0.w = fmaf(wgt, v0.w, a0.w);
          a1.x = fmaf(wgt, v1.x, a1.x); a1.y = fmaf(wgt, v1.y, a1.y);
          a1.z = fmaf(wgt, v1.z, a1.z); a1.w = fmaf(wgt, v1.w, a1.w);
          a2.x = fmaf(wgt, v2.x, a2.x); a2.y = fmaf(wgt, v2.y, a2.y);
          a2.z = fmaf(wgt, v2.z, a2.z); a2.w = fmaf(wgt, v2.w, a2.w);
          a3.x = fmaf(wgt, v3.x, a3.x); a3.y = fmaf(wgt, v3.y, a3.y);
          a3.z = fmaf(wgt, v3.z, a3.z); a3.w = fmaf(wgt, v3.w, a3.w);
        }
      }
    }
  }
  bf16x8 o0, o1;
  o0[0] = (__bf16)a0.x; o0[1] = (__bf16)a0.y; o0[2] = (__bf16)a0.z; o0[3] = (__bf16)a0.w;
  o0[4] = (__bf16)a1.x; o0[5] = (__bf16)a1.y; o0[6] = (__bf16)a1.z; o0[7] = (__bf16)a1.w;
  o1[0] = (__bf16)a2.x; o1[1] = (__bf16)a2.y; o1[2] = (__bf16)a2.z; o1[3] = (__bf16)a2.w;
  o1[4] = (__bf16)a3.x; o1[5] = (__bf16)a3.y; o1[6] = (__bf16)a3.z; o1[7] = (__bf16)a3.w;
  __bf16* op = out + (size_t)bq * DMODEL + hid * 32 + dq;
  *(bf16x8*)(op + 0) = o0;
  *(bf16x8*)(op + 8) = o1;
}

// ---------------------------------------------------------------------------
// xout = LayerNorm(x + res); xb = bf16(xout). If pos: qb = bf16(xout + pos).
// One wave per row.
// ---------------------------------------------------------------------------
__global__ __launch_bounds__(256) void add_ln_kernel(
    const float* __restrict__ x, const float* __restrict__ res,
    const float* __restrict__ g, const float* __restrict__ bta,
    float* __restrict__ xout, __bf16* __restrict__ xb,
    const float* __restrict__ pos, __bf16* __restrict__ qb) {
  int row = blockIdx.x * 4 + (threadIdx.x >> 6);
  int lane = threadIdx.x & 63;
  float4 xv = ((const float4*)(x + (size_t)row * DMODEL))[lane];
  float4 rv = ((const float4*)(res + (size_t)row * DMODEL))[lane];
  xv.x += rv.x; xv.y += rv.y; xv.z += rv.z; xv.w += rv.w;
  float s = xv.x + xv.y + xv.z + xv.w;
  float sq = xv.x * xv.x + xv.y * xv.y + xv.z * xv.z + xv.w * xv.w;
#pragma unroll
  for (int o = 32; o >= 1; o >>= 1) {
    s += __shfl_xor(s, o);
    sq += __shfl_xor(sq, o);
  }
  float mean = s * (1.f / 256.f);
  float var = sq * (1.f / 256.f) - mean * mean;
  float rstd = rsqrtf(var + 1e-5f);
  int c = lane * 4;
  float4 gv = *(const float4*)(g + c);
  float4 bv = *(const float4*)(bta + c);
  float4 o4;
  o4.x = (xv.x - mean) * rstd * gv.x + bv.x;
  o4.y = (xv.y - mean) * rstd * gv.y + bv.y;
  o4.z = (xv.z - mean) * rstd * gv.z + bv.z;
  o4.w = (xv.w - mean) * rstd * gv.w + bv.w;
  ((float4*)(xout + (size_t)row * DMODEL))[lane] = o4;
  bf16x4 ob;
  ob[0] = (__bf16)o4.x; ob[1] = (__bf16)o4.y;
  ob[2] = (__bf16)o4.z; ob[3] = (__bf16)o4.w;
  *(bf16x4*)&xb[(size_t)row * DMODEL + c] = ob;
  if (pos) {
    float4 pv = ((const float4*)(pos + (size_t)row * DMODEL))[lane];
    bf16x4 qv;
    qv[0] = (__bf16)(o4.x + pv.x); qv[1] = (__bf16)(o4.y + pv.y);
    qv[2] = (__bf16)(o4.z + pv.z); qv[3] = (__bf16)(o4.w + pv.w);
    *(bf16x4*)&qb[(size_t)row * DMODEL + c] = qv;
  }
}

// ---------------------------------------------------------------------------
extern "C" void kernel_launch(void* const* d_in, const int* in_sizes, int n_in,
                              void* d_out, int out_size, void* d_ws, size_t ws_size,
                              hipStream_t stream) {
  const float* src0 = (const float*)d_in[0];
  const float* pos0 = (const float*)d_in[1];
  const float* src1 = (const float*)d_in[2];
  const float* pos1 = (const float*)d_in[3];
  const float* src2 = (const float*)d_in[4];
  const float* pos2 = (const float*)d_in[5];
  const float* lvl  = (const float*)d_in[6];
  const float* W_off  = (const float*)d_in[7];
  const float* b_off  = (const float*)d_in[8];
  const float* W_attn = (const float*)d_in[9];
  const float* b_attn = (const float*)d_in[10];
  const float* W_val  = (const float*)d_in[11];
  const float* b_val  = (const float*)d_in[12];
  const float* W_out  = (const float*)d_in[13];
  const float* b_out  = (const float*)d_in[14];
  const float* ln1g = (const float*)d_in[15];
  const float* ln1b = (const float*)d_in[16];
  const float* W_ff1 = (const float*)d_in[17];
  const float* b_ff1 = (const float*)d_in[18];
  const float* W_ff2 = (const float*)d_in[19];
  const float* b_ff2 = (const float*)d_in[20];
  const float* ln2g = (const float*)d_in[21];
  const float* ln2b = (const float*)d_in[22];

  const size_t M = (size_t)MROWS;
  char* w = (char*)d_ws;
  float*  x     = (float*)w;                 w += M * 256 * 4;
  float*  pos   = (float*)w;                 w += M * 256 * 4;
  __bf16* xb    = (__bf16*)w;                w += M * 256 * 2;
  __bf16* qb    = (__bf16*)w;                w += M * 256 * 2;   // alias: attn_bf
  float*  qproj = (float*)w;                 w += M * 384 * 4;   // alias: ffres
  float*  val   = (float*)w;                 w += M * 256 * 4;   // alias: proj
  __bf16* ffh   = (__bf16*)w;                w += M * 1024 * 2;
  __bf16* wqv_t = (__bf16*)w;                w += (size_t)NLAYERS * 640 * 256 * 2;
  __bf16* wout_t= (__bf16*)w;                w += (size_t)NLAYERS * 256 * 256 * 2;
  __bf16* wff1_t= (__bf16*)w;                w += (size_t)NLAYERS * 1024 * 256 * 2;
  __bf16* wff2_t= (__bf16*)w;                w += (size_t)NLAYERS * 256 * 1024 * 2;
  float*  bqv   = (float*)w;                 w += (size_t)NLAYERS * 640 * 4;
  __bf16* attn_bf = qb;
  float*  proj  = val;
  float*  ffres = qproj;

  pack_qv_kernel<<<dim3(640, NLAYERS), 256, 0, stream>>>(
      W_off, W_attn, W_val, b_off, b_attn, b_val, wqv_t, bqv);
  pack_wt_kernel<<<dim3(256, NLAYERS), 256, 0, stream>>>(W_out, wout_t, 256, 256);
  pack_wt_kernel<<<dim3(1024, NLAYERS), 256, 0, stream>>>(W_ff1, wff1_t, 256, 1024);
  pack_wt_kernel<<<dim3(1024, NLAYERS), 256, 0, stream>>>(W_ff2, wff2_t, 1024, 256);

  flatten_kernel<<<dim3(1344, BATCH), 256, 0, stream>>>(
      src0, pos0, src1, pos1, src2, pos2, lvl, x, pos, xb, qb);

  const int MT = MROWS / 128;  // 168
  for (int i = 0; i < NLAYERS; ++i) {
    gemm_qv_kernel<<<dim3(5, MT), 256, 0, stream>>>(
        qb, xb, wqv_t + (size_t)i * 640 * 256, bqv + i * 640, qproj, val);
    deform_kernel<<<MROWS / 16, 256, 0, stream>>>(val, qproj, attn_bf);
    gemm_bf16_kernel<0, 0><<<dim3(2, MT), 256, 0, stream>>>(
        attn_bf, wout_t + (size_t)i * 256 * 256, b_out + i * 256, proj, nullptr, 256, 256);
    add_ln_kernel<<<MROWS / 4, 256, 0, stream>>>(
        x, proj, ln1g + i * 256, ln1b + i * 256, x, xb, nullptr, nullptr);
    gemm_bf16_kernel<1, 1><<<dim3(8, MT), 256, 0, stream>>>(
        xb, wff1_t + (size_t)i * 1024 * 256, b_ff1 + i * 1024, nullptr, ffh, 1024, 256);
    gemm_bf16_kernel<0, 0><<<dim3(2, MT), 256, 0, stream>>>(
        ffh, wff2_t + (size_t)i * 256 * 1024, b_ff2 + i * 256, ffres, nullptr, 256, 1024);
    float* xdst = (i == NLAYERS - 1) ? (float*)d_out : x;
    add_ln_kernel<<<MROWS / 4, 256, 0, stream>>>(
        x, ffres, ln2g + i * 256, ln2b + i * 256, xdst, xb, pos, qb);
  }
}

// Round 5
// 1017.303 us; speedup vs baseline: 1.1809x; 1.1809x over previous
//
#include <hip/hip_runtime.h>

// MSDeformAttn pixel decoder. v4: bf16 val (half gather bytes), deform
// 32thr/query (1x bf16x8 load per corner). LDS-transpose flatten, qb fused
// into LN2. bf16-MFMA GEMMs (fused qproj|val N=640).
// D=256, NH=8, DH=32, NL=3, NP=4, DFF=1024, B=4, Q=5376, M=B*Q=21504.

#define DMODEL 256
#define NLAYERS 6
#define BATCH 4
#define QTOT 5376
#define MROWS (BATCH * QTOT)   // 21504 = 168*128

typedef __bf16 bf16x8 __attribute__((ext_vector_type(8)));
typedef __bf16 bf16x4 __attribute__((ext_vector_type(4)));
typedef float floatx4 __attribute__((ext_vector_type(4)));

// ---------------------------------------------------------------------------
// Flatten via LDS tile transpose. Per block: one 32x32 (d x p) tile of one
// (batch, level). Writes x fp32, xb bf16, pos fp32, qb bf16.
// ---------------------------------------------------------------------------
__global__ __launch_bounds__(256) void flatten_kernel(
    const float* __restrict__ s0, const float* __restrict__ p0,
    const float* __restrict__ s1, const float* __restrict__ p1,
    const float* __restrict__ s2, const float* __restrict__ p2,
    const float* __restrict__ lvl, float* __restrict__ x,
    float* __restrict__ pos, __bf16* __restrict__ xb,
    __bf16* __restrict__ qb) {
  __shared__ float ls[32][33];
  __shared__ float lp[32][33];
  int b = blockIdx.y;
  int tile = blockIdx.x;
  const float* sp; const float* pp; int l, hw, tp, td, qbase;
  if (tile < 1024)      { l = 0; hw = 4096; int t = tile;        td = t & 7; tp = t >> 3; qbase = 0; sp = s0; pp = p0; }
  else if (tile < 1280) { l = 1; hw = 1024; int t = tile - 1024; td = t & 7; tp = t >> 3; qbase = 4096; sp = s1; pp = p1; }
  else                  { l = 2; hw = 256;  int t = tile - 1280; td = t & 7; tp = t >> 3; qbase = 5120; sp = s2; pp = p2; }
  int tx = threadIdx.x & 31, ty = threadIdx.x >> 5;
  int d0 = td * 32, pbase = tp * 32;
#pragma unroll
  for (int r = 0; r < 4; ++r) {
    int dl = r * 8 + ty;
    size_t gi = ((size_t)(b * DMODEL + d0 + dl)) * hw + pbase + tx;
    ls[dl][tx] = sp[gi];
    lp[dl][tx] = pp[gi];
  }
  __syncthreads();
  int d = d0 + tx;
  float lv = lvl[l * DMODEL + d];
#pragma unroll
  for (int r = 0; r < 4; ++r) {
    int pl = r * 8 + ty;
    size_t bq = (size_t)b * QTOT + qbase + pbase + pl;
    float xv = ls[tx][pl];
    float pv = lp[tx][pl] + lv;
    x[bq * DMODEL + d] = xv;
    xb[bq * DMODEL + d] = (__bf16)xv;
    pos[bq * DMODEL + d] = pv;
    qb[bq * DMODEL + d] = (__bf16)(xv + pv);
  }
}

// ---------------------------------------------------------------------------
// Weight pack: W [L][K][N] fp32 -> Wt [L][N][K] bf16 (transposed)
// ---------------------------------------------------------------------------
__global__ __launch_bounds__(256) void pack_wt_kernel(
    const float* __restrict__ W, __bf16* __restrict__ Wt, int K, int N) {
  int l = blockIdx.y;
  int idx = blockIdx.x * 256 + threadIdx.x;
  int n = idx / K, k = idx - n * K;
  Wt[(size_t)l * N * K + idx] = (__bf16)W[(size_t)l * K * N + (size_t)k * N + n];
}

// Combined [W_off|W_attn|pad|W_val] pack -> Wt [L][640][256] bf16 + bias [L][640]
__global__ __launch_bounds__(256) void pack_qv_kernel(
    const float* __restrict__ Woff, const float* __restrict__ Wattn,
    const float* __restrict__ Wval,
    const float* __restrict__ boff, const float* __restrict__ battn,
    const float* __restrict__ bval,
    __bf16* __restrict__ Wt, float* __restrict__ bc) {
  int l = blockIdx.y;
  int n = blockIdx.x;          // 0..639
  int k = threadIdx.x;         // 0..255
  float v = 0.f;
  if (n < 192)      v = Woff[((size_t)l * 256 + k) * 192 + n];
  else if (n < 288) v = Wattn[((size_t)l * 256 + k) * 96 + (n - 192)];
  else if (n >= 384) v = Wval[((size_t)l * 256 + k) * 256 + (n - 384)];
  Wt[((size_t)l * 640 + n) * 256 + k] = (__bf16)v;
  if (k == 0) {
    float b = 0.f;
    if (n < 192)      b = boff[l * 192 + n];
    else if (n < 288) b = battn[l * 96 + (n - 192)];
    else if (n >= 384) b = bval[l * 256 + (n - 384)];
    bc[l * 640 + n] = b;
  }
}

// ---------------------------------------------------------------------------
// Shared MFMA tile core: acc[4][4] over 128x128 tile, BK=32, 4 waves (2x2).
// ---------------------------------------------------------------------------
#define GEMM_CORE(A_, B_, K_)                                                  \
  for (int k0 = 0; k0 < (K_); k0 += 32) {                                      \
    __syncthreads();                                                           \
    _Pragma("unroll")                                                          \
    for (int cc = 0; cc < 2; ++cc) {                                           \
      int c = wid * 2 + cc;                                                    \
      __builtin_amdgcn_global_load_lds(                                        \
          (__attribute__((address_space(1))) void*)((A_) + (size_t)c * 16 * (K_) + k0), \
          (__attribute__((address_space(3))) void*)(As + c * 512), 16, 0, 0);  \
      __builtin_amdgcn_global_load_lds(                                        \
          (__attribute__((address_space(1))) void*)((B_) + (size_t)c * 16 * (K_) + k0), \
          (__attribute__((address_space(3))) void*)(Bs + c * 512), 16, 0, 0);  \
    }                                                                          \
    __syncthreads();                                                           \
    bf16x8 af[4], bfr[4];                                                      \
    _Pragma("unroll")                                                          \
    for (int i = 0; i < 4; ++i)                                                \
      af[i] = *(const bf16x8*)&As[(wr * 64 + i * 16 + (lane & 15)) * 32 + (lane >> 4) * 8]; \
    _Pragma("unroll")                                                          \
    for (int j = 0; j < 4; ++j)                                                \
      bfr[j] = *(const bf16x8*)&Bs[(wc * 64 + j * 16 + (lane & 15)) * 32 + (lane >> 4) * 8]; \
    _Pragma("unroll")                                                          \
    for (int i = 0; i < 4; ++i)                                                \
      _Pragma("unroll")                                                        \
      for (int j = 0; j < 4; ++j)                                              \
        acc[i][j] = __builtin_amdgcn_mfma_f32_16x16x32_bf16(af[i], bfr[j], acc[i][j], 0, 0, 0); \
  }

// ---------------------------------------------------------------------------
// Generic bf16 GEMM: C = A[M,K] @ Wt[N,K]^T + bias
// ---------------------------------------------------------------------------
template<int RELU, int BF16OUT>
__global__ __launch_bounds__(256) void gemm_bf16_kernel(
    const __bf16* __restrict__ A, const __bf16* __restrict__ Wt,
    const float* __restrict__ bias, float* __restrict__ C,
    __bf16* __restrict__ Cb, int N, int K) {
  __shared__ __bf16 As[128 * 32];
  __shared__ __bf16 Bs[128 * 32];
  int t = threadIdx.x;
  int lane = t & 63, wid = t >> 6;
  int wr = wid >> 1, wc = wid & 1;
  int row0 = blockIdx.y * 128;
  int n0 = blockIdx.x * 128;
  floatx4 acc[4][4] = {};
  int srow = lane >> 2;
  int skoff = (lane & 3) * 8;
  const __bf16* Abase = A + (size_t)(row0 + srow) * K + skoff;
  const __bf16* Bbase = Wt + (size_t)(n0 + srow) * K + skoff;
  GEMM_CORE(Abase, Bbase, K)
  int orow = row0 + wr * 64 + (lane >> 4) * 4;
  int ocol = n0 + wc * 64 + (lane & 15);
#pragma unroll
  for (int i = 0; i < 4; ++i)
#pragma unroll
    for (int j = 0; j < 4; ++j) {
      int col = ocol + j * 16;
      float bv = bias[col];
#pragma unroll
      for (int r = 0; r < 4; ++r) {
        int row = orow + i * 16 + r;
        float v = acc[i][j][r] + bv;
        if (RELU) v = fmaxf(v, 0.f);
        if (BF16OUT) Cb[(size_t)row * N + col] = (__bf16)v;
        else         C[(size_t)row * N + col] = v;
      }
    }
}

// ---------------------------------------------------------------------------
// Fused [qproj|val] GEMM: bn<3 -> qproj fp32 (stride 384),
//                          bn>=3 -> val bf16 (stride 256)
// ---------------------------------------------------------------------------
__global__ __launch_bounds__(256) void gemm_qv_kernel(
    const __bf16* __restrict__ qb, const __bf16* __restrict__ xb,
    const __bf16* __restrict__ Wt, const float* __restrict__ bias,
    float* __restrict__ qproj, __bf16* __restrict__ valb) {
  __shared__ __bf16 As[128 * 32];
  __shared__ __bf16 Bs[128 * 32];
  int t = threadIdx.x;
  int lane = t & 63, wid = t >> 6;
  int wr = wid >> 1, wc = wid & 1;
  int bn = blockIdx.x;                    // 0..4
  int row0 = blockIdx.y * 128;
  int n0 = bn * 128;
  const __bf16* A = (bn < 3) ? qb : xb;
  floatx4 acc[4][4] = {};
  int srow = lane >> 2;
  int skoff = (lane & 3) * 8;
  const __bf16* Abase = A + (size_t)(row0 + srow) * 256 + skoff;
  const __bf16* Bbase = Wt + (size_t)(n0 + srow) * 256 + skoff;
  GEMM_CORE(Abase, Bbase, 256)
  int orow = row0 + wr * 64 + (lane >> 4) * 4;
  int ocol = wc * 64 + (lane & 15);
#pragma unroll
  for (int i = 0; i < 4; ++i)
#pragma unroll
    for (int j = 0; j < 4; ++j) {
      int col = ocol + j * 16;
      float bv = bias[n0 + col];
#pragma unroll
      for (int r = 0; r < 4; ++r) {
        int row = orow + i * 16 + r;
        float v = acc[i][j][r] + bv;
        if (bn < 3) qproj[(size_t)row * 384 + n0 + col] = v;
        else        valb[(size_t)row * 256 + (n0 - 384) + col] = (__bf16)v;
      }
    }
}

// ---------------------------------------------------------------------------
// Deformable sampling + per-head softmax. 32 threads/query: hid = tq>>2,
// 8 channels per thread (one bf16x8 = 16B gather per corner). Output bf16.
// ---------------------------------------------------------------------------
__global__ __launch_bounds__(256) void deform_kernel(
    const __bf16* __restrict__ val, const float* __restrict__ qproj,
    __bf16* __restrict__ out) {
  int bq = blockIdx.x * 8 + (threadIdx.x >> 5);
  int b = bq / QTOT, q = bq % QTOT;
  int tq = threadIdx.x & 31;
  int hid = tq >> 2, dq = (tq & 3) * 8;

  int p, wsrc;
  if (q < 4096)      { p = q;        wsrc = 64; }
  else if (q < 5120) { p = q - 4096; wsrc = 32; }
  else               { p = q - 5120; wsrc = 16; }
  float inv = 1.0f / (float)wsrc;
  float refx = ((float)(p % wsrc) + 0.5f) * inv;
  float refy = ((float)(p / wsrc) + 0.5f) * inv;

  const float* base = qproj + (size_t)bq * 384;
  float aw[12], ob[24];
  *(float4*)&aw[0] = *(const float4*)(base + 192 + hid * 12);
  *(float4*)&aw[4] = *(const float4*)(base + 192 + hid * 12 + 4);
  *(float4*)&aw[8] = *(const float4*)(base + 192 + hid * 12 + 8);
#pragma unroll
  for (int i = 0; i < 6; ++i)
    *(float4*)&ob[i * 4] = *(const float4*)(base + hid * 24 + i * 4);

  float mx = -1e30f;
#pragma unroll
  for (int k = 0; k < 12; ++k) mx = fmaxf(mx, aw[k]);
  float s = 0.f;
#pragma unroll
  for (int k = 0; k < 12; ++k) { aw[k] = __expf(aw[k] - mx); s += aw[k]; }
  float invs = 1.0f / s;
#pragma unroll
  for (int k = 0; k < 12; ++k) aw[k] *= invs;

  const __bf16* vb = val + ((size_t)b * QTOT) * DMODEL + hid * 32 + dq;

  const int starts[3] = {0, 4096, 5120};
  const int wls[3] = {64, 32, 16};
  float acc[8] = {};
#pragma unroll
  for (int l = 0; l < 3; ++l) {
    int wl = wls[l], start = starts[l];
    float fwl = (float)wl;
#pragma unroll
    for (int pp = 0; pp < 4; ++pp) {
      float wcomb = aw[l * 4 + pp];
      float fx = refx * fwl + ob[(l * 4 + pp) * 2 + 0] - 0.5f;
      float fy = refy * fwl + ob[(l * 4 + pp) * 2 + 1] - 0.5f;
      float x0f = floorf(fx), y0f = floorf(fy);
      float lx = fx - x0f, ly = fy - y0f;
      int x0 = (int)x0f, y0 = (int)y0f;
#pragma unroll
      for (int c = 0; c < 4; ++c) {
        int dx = c & 1, dy = c >> 1;
        int xi = x0 + dx, yi = y0 + dy;
        if (xi >= 0 && xi < wl && yi >= 0 && yi < wl) {
          float wgt = (dx ? lx : 1.f - lx) * (dy ? ly : 1.f - ly) * wcomb;
          bf16x8 v = *(const bf16x8*)(vb + (size_t)(start + yi * wl + xi) * DMODEL);
#pragma unroll
          for (int e = 0; e < 8; ++e)
            acc[e] = fmaf(wgt, (float)v[e], acc[e]);
        }
      }
    }
  }
  bf16x8 o;
#pragma unroll
  for (int e = 0; e < 8; ++e) o[e] = (__bf16)acc[e];
  *(bf16x8*)(out + (size_t)bq * DMODEL + hid * 32 + dq) = o;
}

// ---------------------------------------------------------------------------
// xout = LayerNorm(x + res); xb = bf16(xout). If pos: qb = bf16(xout + pos).
// One wave per row.
// ---------------------------------------------------------------------------
__global__ __launch_bounds__(256) void add_ln_kernel(
    const float* __restrict__ x, const float* __restrict__ res,
    const float* __restrict__ g, const float* __restrict__ bta,
    float* __restrict__ xout, __bf16* __restrict__ xb,
    const float* __restrict__ pos, __bf16* __restrict__ qb) {
  int row = blockIdx.x * 4 + (threadIdx.x >> 6);
  int lane = threadIdx.x & 63;
  float4 xv = ((const float4*)(x + (size_t)row * DMODEL))[lane];
  float4 rv = ((const float4*)(res + (size_t)row * DMODEL))[lane];
  xv.x += rv.x; xv.y += rv.y; xv.z += rv.z; xv.w += rv.w;
  float s = xv.x + xv.y + xv.z + xv.w;
  float sq = xv.x * xv.x + xv.y * xv.y + xv.z * xv.z + xv.w * xv.w;
#pragma unroll
  for (int o = 32; o >= 1; o >>= 1) {
    s += __shfl_xor(s, o);
    sq += __shfl_xor(sq, o);
  }
  float mean = s * (1.f / 256.f);
  float var = sq * (1.f / 256.f) - mean * mean;
  float rstd = rsqrtf(var + 1e-5f);
  int c = lane * 4;
  float4 gv = *(const float4*)(g + c);
  float4 bv = *(const float4*)(bta + c);
  float4 o4;
  o4.x = (xv.x - mean) * rstd * gv.x + bv.x;
  o4.y = (xv.y - mean) * rstd * gv.y + bv.y;
  o4.z = (xv.z - mean) * rstd * gv.z + bv.z;
  o4.w = (xv.w - mean) * rstd * gv.w + bv.w;
  ((float4*)(xout + (size_t)row * DMODEL))[lane] = o4;
  bf16x4 ob;
  ob[0] = (__bf16)o4.x; ob[1] = (__bf16)o4.y;
  ob[2] = (__bf16)o4.z; ob[3] = (__bf16)o4.w;
  *(bf16x4*)&xb[(size_t)row * DMODEL + c] = ob;
  if (pos) {
    float4 pv = ((const float4*)(pos + (size_t)row * DMODEL))[lane];
    bf16x4 qv;
    qv[0] = (__bf16)(o4.x + pv.x); qv[1] = (__bf16)(o4.y + pv.y);
    qv[2] = (__bf16)(o4.z + pv.z); qv[3] = (__bf16)(o4.w + pv.w);
    *(bf16x4*)&qb[(size_t)row * DMODEL + c] = qv;
  }
}

// ---------------------------------------------------------------------------
extern "C" void kernel_launch(void* const* d_in, const int* in_sizes, int n_in,
                              void* d_out, int out_size, void* d_ws, size_t ws_size,
                              hipStream_t stream) {
  const float* src0 = (const float*)d_in[0];
  const float* pos0 = (const float*)d_in[1];
  const float* src1 = (const float*)d_in[2];
  const float* pos1 = (const float*)d_in[3];
  const float* src2 = (const float*)d_in[4];
  const float* pos2 = (const float*)d_in[5];
  const float* lvl  = (const float*)d_in[6];
  const float* W_off  = (const float*)d_in[7];
  const float* b_off  = (const float*)d_in[8];
  const float* W_attn = (const float*)d_in[9];
  const float* b_attn = (const float*)d_in[10];
  const float* W_val  = (const float*)d_in[11];
  const float* b_val  = (const float*)d_in[12];
  const float* W_out  = (const float*)d_in[13];
  const float* b_out  = (const float*)d_in[14];
  const float* ln1g = (const float*)d_in[15];
  const float* ln1b = (const float*)d_in[16];
  const float* W_ff1 = (const float*)d_in[17];
  const float* b_ff1 = (const float*)d_in[18];
  const float* W_ff2 = (const float*)d_in[19];
  const float* b_ff2 = (const float*)d_in[20];
  const float* ln2g = (const float*)d_in[21];
  const float* ln2b = (const float*)d_in[22];

  const size_t M = (size_t)MROWS;
  char* w = (char*)d_ws;
  float*  x     = (float*)w;                 w += M * 256 * 4;
  float*  pos   = (float*)w;                 w += M * 256 * 4;
  __bf16* xb    = (__bf16*)w;                w += M * 256 * 2;
  __bf16* qb    = (__bf16*)w;                w += M * 256 * 2;   // alias: attn_bf
  float*  qproj = (float*)w;                 w += M * 384 * 4;   // alias: ffres
  __bf16* valb  = (__bf16*)w;                w += M * 256 * 2;
  __bf16* ffh   = (__bf16*)w;                w += M * 1024 * 2;  // alias: proj (fp32)
  __bf16* wqv_t = (__bf16*)w;                w += (size_t)NLAYERS * 640 * 256 * 2;
  __bf16* wout_t= (__bf16*)w;                w += (size_t)NLAYERS * 256 * 256 * 2;
  __bf16* wff1_t= (__bf16*)w;                w += (size_t)NLAYERS * 1024 * 256 * 2;
  __bf16* wff2_t= (__bf16*)w;                w += (size_t)NLAYERS * 256 * 1024 * 2;
  float*  bqv   = (float*)w;                 w += (size_t)NLAYERS * 640 * 4;
  __bf16* attn_bf = qb;
  float*  proj  = (float*)ffh;   // proj consumed by LN1 before ffh written
  float*  ffres = qproj;

  pack_qv_kernel<<<dim3(640, NLAYERS), 256, 0, stream>>>(
      W_off, W_attn, W_val, b_off, b_attn, b_val, wqv_t, bqv);
  pack_wt_kernel<<<dim3(256, NLAYERS), 256, 0, stream>>>(W_out, wout_t, 256, 256);
  pack_wt_kernel<<<dim3(1024, NLAYERS), 256, 0, stream>>>(W_ff1, wff1_t, 256, 1024);
  pack_wt_kernel<<<dim3(1024, NLAYERS), 256, 0, stream>>>(W_ff2, wff2_t, 1024, 256);

  flatten_kernel<<<dim3(1344, BATCH), 256, 0, stream>>>(
      src0, pos0, src1, pos1, src2, pos2, lvl, x, pos, xb, qb);

  const int MT = MROWS / 128;  // 168
  for (int i = 0; i < NLAYERS; ++i) {
    gemm_qv_kernel<<<dim3(5, MT), 256, 0, stream>>>(
        qb, xb, wqv_t + (size_t)i * 640 * 256, bqv + i * 640, qproj, valb);
    deform_kernel<<<MROWS / 8, 256, 0, stream>>>(valb, qproj, attn_bf);
    gemm_bf16_kernel<0, 0><<<dim3(2, MT), 256, 0, stream>>>(
        attn_bf, wout_t + (size_t)i * 256 * 256, b_out + i * 256, proj, nullptr, 256, 256);
    add_ln_kernel<<<MROWS / 4, 256, 0, stream>>>(
        x, proj, ln1g + i * 256, ln1b + i * 256, x, xb, nullptr, nullptr);
    gemm_bf16_kernel<1, 1><<<dim3(8, MT), 256, 0, stream>>>(
        xb, wff1_t + (size_t)i * 1024 * 256, b_ff1 + i * 1024, nullptr, ffh, 1024, 256);
    gemm_bf16_kernel<0, 0><<<dim3(2, MT), 256, 0, stream>>>(
        ffh, wff2_t + (size_t)i * 256 * 1024, b_ff2 + i * 256, ffres, nullptr, 256, 1024);
    float* xdst = (i == NLAYERS - 1) ? (float*)d_out : x;
    add_ln_kernel<<<MROWS / 4, 256, 0, stream>>>(
        x, ffres, ln2g + i * 256, ln2b + i * 256, xdst, xb, pos, qb);
  }
}